// Round 4
// baseline (702.227 us; speedup 1.0000x reference)
//
#include <hip/hip_runtime.h>
#include <hip/hip_bf16.h>
#include <cstdint>
#include <cstddef>

typedef __bf16 bf16_t;
typedef __bf16 bf16x8 __attribute__((ext_vector_type(8)));
typedef float floatx4 __attribute__((ext_vector_type(4)));

#define BATCH 4
#define SEQ   2048
#define DMODEL 2048
#define NHEADS 16
#define HDIM  128
#define MTOK  (BATCH * SEQ)   // 8192

// async global->LDS, 16B per lane; LDS dest = wave-uniform base + lane*16
__device__ __forceinline__ void gload_lds16(const bf16_t* g, bf16_t* l) {
  __builtin_amdgcn_global_load_lds(
      (const __attribute__((address_space(1))) void*)g,
      (__attribute__((address_space(3))) void*)l, 16, 0, 0);
}

// ---------------- dtype detector ----------------
__global__ void detect_dtype(const unsigned* __restrict__ x, int* __restrict__ flag) {
  __shared__ int cnt[256];
  const int t = threadIdx.x;
  int c = 0;
  for (int i = 0; i < 8; i++) {
    unsigned w = x[t * 8 + i];
    unsigned e = (w >> 7) & 0xFFu;
    c += (e >= 100u && e <= 140u) ? 1 : 0;
  }
  cnt[t] = c;
  __syncthreads();
  for (int s = 128; s > 0; s >>= 1) {
    if (t < s) cnt[t] += cnt[t + s];
    __syncthreads();
  }
  if (t == 0) *flag = (cnt[0] > 1433) ? 1 : 0;
}

__device__ __forceinline__ bf16x8 cvt8(const float* __restrict__ p) {
  float4 a = *(const float4*)p;
  float4 b = *(const float4*)(p + 4);
  bf16x8 o;
  o[0] = (bf16_t)a.x; o[1] = (bf16_t)a.y; o[2] = (bf16_t)a.z; o[3] = (bf16_t)a.w;
  o[4] = (bf16_t)b.x; o[5] = (bf16_t)b.y; o[6] = (bf16_t)b.z; o[7] = (bf16_t)b.w;
  return o;
}

__global__ void convert_to_bf16(const void* __restrict__ src, bf16_t* __restrict__ dst,
                                int n, const int* __restrict__ flag) {
  const int i = (blockIdx.x * blockDim.x + threadIdx.x) * 8;
  if (i >= n) return;
  if (*flag) *(bf16x8*)(dst + i) = *(const bf16x8*)((const bf16_t*)src + i);
  else       *(bf16x8*)(dst + i) = cvt8((const float*)src + i);
}

// ================= 256x256 8-phase GEMM =================
// m201-faithful sync: bare builtin s_barrier pairs per phase, clobber-free
// counted vmcnt(8) at ends of ph1/ph3, asm lgkmcnt(0) after the pre-MFMA
// barrier. NO sched_barrier(0) anywhere (m141: order-pinning defeats the
// scheduler), NO memory clobbers (r2: forces vmcnt drains).
// LDS: 2 buf x 2 khalf x [256 rows][32 k] x {A,B} = 128 KiB. 64B row stride
// -> frag ds_read_b128 hits every bank uniformly (8 accesses/bank = floor).
// Stage stream (1 half-tile/phase): ph0:A1(kt+1) ph1:B1(kt+1)
//                                   ph2:A0(kt+2) ph3:B0(kt+2)
template<bool BIAS, bool OUT_DYN>
__global__ __launch_bounds__(512, 2)
void gemm256(const bf16_t* __restrict__ A, const bf16_t* __restrict__ B,
             const bf16_t* __restrict__ biasv, void* __restrict__ Cv,
             int M, int N, int K, const int* __restrict__ flag, float scale) {
  const bool isbf = (*flag != 0);
  __shared__ alignas(16) bf16_t sA[2][2][256 * 32];
  __shared__ alignas(16) bf16_t sB[2][2][256 * 32];
  const int tid  = threadIdx.x;
  const int lane = tid & 63;
  const int wave = tid >> 6;
  const int wm = wave >> 2, wn = wave & 3;   // 2 x 4
  const int q4 = lane >> 4, l16 = lane & 15;
  const int m0 = blockIdx.y * 256;
  const int n0 = blockIdx.x * 256;
  const int NT = K >> 6;                     // K-tiles of BK=64

  auto STG = [&](const bf16_t* __restrict__ G, int grow0, bf16_t* slot, int kt, int kh) {
    #pragma unroll
    for (int j = 0; j < 2; ++j) {
      const int c = (wave * 2 + j) * 64 + lane;   // granule 0..1023
      const int row = c >> 2, c8 = c & 3;
      gload_lds16(G + (size_t)(grow0 + row) * K + (kt * 64 + kh * 32 + c8 * 8),
                  slot + (wave * 2 + j) * 512);
    }
  };

  floatx4 acc[8][4] = {};

  const int aoff = (wm * 128 + l16) * 32 + q4 * 8;
  const int boff = (wn * 64  + l16) * 32 + q4 * 8;

  // prologue: A0(0) B0(0) A1(0) B1(0) A0(1) B0(1) -> 12 vmem ops/wave
  STG(A, m0, &sA[0][0][0], 0, 0);
  STG(B, n0, &sB[0][0][0], 0, 0);
  STG(A, m0, &sA[0][1][0], 0, 1);
  STG(B, n0, &sB[0][1][0], 0, 1);
  STG(A, m0, &sA[1][0][0], 1, 0);
  STG(B, n0, &sB[1][0][0], 1, 0);
  asm volatile("s_waitcnt vmcnt(8)");               // A0(0),B0(0) landed
  __builtin_amdgcn_s_barrier();

  #pragma unroll 2
  for (int kt = 0; kt < NT; ++kt) {
    const int buf = kt & 1;
    const bf16_t* sA0 = &sA[buf][0][0];
    const bf16_t* sA1 = &sA[buf][1][0];
    const bf16_t* sB0 = &sB[buf][0][0];
    const bf16_t* sB1 = &sB[buf][1][0];
    bf16x8 af[4], bfr[4];

    // ---- phase 0: khalf0, mhalf0 ----
    #pragma unroll
    for (int mf = 0; mf < 4; mf++) af[mf]  = *(const bf16x8*)(sA0 + aoff + mf * 512);
    #pragma unroll
    for (int nf = 0; nf < 4; nf++) bfr[nf] = *(const bf16x8*)(sB0 + boff + nf * 512);
    if (kt + 1 < NT) STG(A, m0, &sA[buf ^ 1][1][0], kt + 1, 1);
    __builtin_amdgcn_s_barrier();
    asm volatile("s_waitcnt lgkmcnt(0)");
    __builtin_amdgcn_s_setprio(1);
    #pragma unroll
    for (int mf = 0; mf < 4; mf++)
      #pragma unroll
      for (int nf = 0; nf < 4; nf++)
        acc[mf][nf] = __builtin_amdgcn_mfma_f32_16x16x32_bf16(af[mf], bfr[nf], acc[mf][nf], 0, 0, 0);
    __builtin_amdgcn_s_setprio(0);
    __builtin_amdgcn_s_barrier();

    // ---- phase 1: khalf0, mhalf1 (reuse bfr regs) ----
    #pragma unroll
    for (int mf = 0; mf < 4; mf++) af[mf] = *(const bf16x8*)(sA0 + aoff + (64 * 32) + mf * 512);
    if (kt + 1 < NT) STG(B, n0, &sB[buf ^ 1][1][0], kt + 1, 1);
    __builtin_amdgcn_s_barrier();
    asm volatile("s_waitcnt lgkmcnt(0)");
    __builtin_amdgcn_s_setprio(1);
    #pragma unroll
    for (int mf = 0; mf < 4; mf++)
      #pragma unroll
      for (int nf = 0; nf < 4; nf++)
        acc[4 + mf][nf] = __builtin_amdgcn_mfma_f32_16x16x32_bf16(af[mf], bfr[nf], acc[4 + mf][nf], 0, 0, 0);
    __builtin_amdgcn_s_setprio(0);
    if (kt < NT - 1) asm volatile("s_waitcnt vmcnt(8)");  // A1(kt),B1(kt) landed
    else             asm volatile("s_waitcnt vmcnt(0)");
    __builtin_amdgcn_s_barrier();

    // ---- phase 2: khalf1, mhalf0 ----
    #pragma unroll
    for (int mf = 0; mf < 4; mf++) af[mf]  = *(const bf16x8*)(sA1 + aoff + mf * 512);
    #pragma unroll
    for (int nf = 0; nf < 4; nf++) bfr[nf] = *(const bf16x8*)(sB1 + boff + nf * 512);
    if (kt + 2 < NT) STG(A, m0, &sA[buf][0][0], kt + 2, 0);
    __builtin_amdgcn_s_barrier();
    asm volatile("s_waitcnt lgkmcnt(0)");
    __builtin_amdgcn_s_setprio(1);
    #pragma unroll
    for (int mf = 0; mf < 4; mf++)
      #pragma unroll
      for (int nf = 0; nf < 4; nf++)
        acc[mf][nf] = __builtin_amdgcn_mfma_f32_16x16x32_bf16(af[mf], bfr[nf], acc[mf][nf], 0, 0, 0);
    __builtin_amdgcn_s_setprio(0);
    __builtin_amdgcn_s_barrier();

    // ---- phase 3: khalf1, mhalf1 (reuse bfr regs) ----
    #pragma unroll
    for (int mf = 0; mf < 4; mf++) af[mf] = *(const bf16x8*)(sA1 + aoff + (64 * 32) + mf * 512);
    if (kt + 2 < NT) STG(B, n0, &sB[buf][0][0], kt + 2, 0);
    __builtin_amdgcn_s_barrier();
    asm volatile("s_waitcnt lgkmcnt(0)");
    __builtin_amdgcn_s_setprio(1);
    #pragma unroll
    for (int mf = 0; mf < 4; mf++)
      #pragma unroll
      for (int nf = 0; nf < 4; nf++)
        acc[4 + mf][nf] = __builtin_amdgcn_mfma_f32_16x16x32_bf16(af[mf], bfr[nf], acc[4 + mf][nf], 0, 0, 0);
    __builtin_amdgcn_s_setprio(0);
    if (kt < NT - 2)       asm volatile("s_waitcnt vmcnt(8)");  // A0(kt+1),B0(kt+1)
    else if (kt == NT - 2) asm volatile("s_waitcnt vmcnt(4)");
    __builtin_amdgcn_s_barrier();
  }

  // epilogue
  #pragma unroll
  for (int mf = 0; mf < 8; mf++) {
    const int mrow = m0 + wm * 128 + mf * 16 + q4 * 4;
    #pragma unroll
    for (int nf = 0; nf < 4; nf++) {
      const int ncol = n0 + wn * 64 + nf * 16 + l16;
      float badd = 0.0f;
      if (BIAS) badd = (float)biasv[ncol];
      #pragma unroll
      for (int r = 0; r < 4; r++) {
        const size_t idx = (size_t)(mrow + r) * N + ncol;
        const float val = acc[mf][nf][r] * scale + badd;
        if (OUT_DYN && !isbf) ((float*)Cv)[idx] = val;
        else                  ((bf16_t*)Cv)[idx] = (bf16_t)val;
      }
    }
  }
}

// ---------------- Flash attention, causal, fixed-max softmax ----------------
// 1D grid 1024: i = x*64 + bh  (bh = b*16+h, x = q-tile index).
//  - i%8 = bh%8  -> all 16 q-tiles of one (b,h) land on ONE XCD: its 1MB
//    K+VT panel stays L2-resident (T1 mechanism: inter-block panel reuse).
//  - CU c holds blocks {c, c+256, ...} -> x in {x0, x0+4, x0+8, x0+12}:
//    big and small causal tiles mix on every CU (load balance, no pairing).
// sP stride 40 -> 32 (P tile is exactly 32 wide): LDS 43008 -> 40960 B
// = 4 blocks/CU (was 2).  __launch_bounds__(256,4).
__global__ __launch_bounds__(256, 4)
void attn_fused(const bf16_t* __restrict__ Qb, const bf16_t* __restrict__ Kb,
                const bf16_t* __restrict__ VTb, bf16_t* __restrict__ ctx) {
  __shared__ alignas(16) bf16_t sK[2][32 * 128];   // xor-swizzled 16B granules
  __shared__ alignas(16) bf16_t sVT[2][128 * 32];  // [d][t], 64B rows
  __shared__ alignas(16) bf16_t sP[4 * 32 * 32];   // per-wave [32 q][32]

  const int tid = threadIdx.x, lane = tid & 63, wave = tid >> 6;
  const int q4 = lane >> 4, l16 = lane & 15;
  const int bid = blockIdx.x;
  const int bh = bid & 63;
  const int x  = bid >> 6;
  const int b  = bh >> 4;
  const int h  = bh & 15;
  const int q0 = (15 - x) * 128;               // big tiles at low ids
  const int qw = q0 + wave * 32;
  const size_t qkbase = (size_t)b * SEQ * DMODEL + (size_t)h * HDIM;
  const size_t vtbase = (size_t)(h * HDIM) * MTOK + (size_t)b * SEQ;
  bf16_t* sPw = sP + wave * 1024;

  auto STAGE = [&](int kt, int bs) {
    const int kb = kt * 32;
    #pragma unroll
    for (int j = 0; j < 2; ++j) {
      const int c = (wave * 2 + j) * 64 + lane;   // K: 32 rows x 16 granules
      const int row = c >> 4;
      const int gg = (c & 15) ^ (row & 15);       // xor swizzle
      gload_lds16(Kb + qkbase + (size_t)(kb + row) * DMODEL + gg * 8,
                  sK[bs] + (wave * 2 + j) * 512);
    }
    #pragma unroll
    for (int j = 0; j < 2; ++j) {
      const int c = (wave * 2 + j) * 64 + lane;   // VT: 128 rows x 4 granules
      const int row = c >> 2, g = c & 3;
      gload_lds16(VTb + vtbase + (size_t)row * MTOK + (kb + g * 8),
                  sVT[bs] + (wave * 2 + j) * 512);
    }
  };

  // Q A-frags
  bf16x8 qf[2][4];
  #pragma unroll
  for (int mb = 0; mb < 2; mb++) {
    const bf16_t* qp = Qb + qkbase + (size_t)(qw + mb * 16 + l16) * DMODEL + q4 * 8;
    #pragma unroll
    for (int kc = 0; kc < 4; kc++) qf[mb][kc] = *(const bf16x8*)(qp + kc * 32);
  }

  floatx4 o[2][8] = {};
  float rs[2][4] = {};
  const int ntiles = q0 / 32 + 4;

  STAGE(0, 0);
  __syncthreads();

  for (int kt = 0; kt < ntiles; ++kt) {
    const int cur = kt & 1;
    if (kt + 1 < ntiles) STAGE(kt + 1, cur ^ 1);
    const int kb = kt * 32;

    if (kb < qw + 32) {   // skip fully-masked tiles (wave-uniform)
      floatx4 s[2][2] = {};
      #pragma unroll
      for (int kc = 0; kc < 4; kc++) {
        const int sw = (kc * 4 + q4) ^ l16;
        bf16x8 kf0 = *(const bf16x8*)(sK[cur] + ((l16)      * 16 + sw) * 8);
        bf16x8 kf1 = *(const bf16x8*)(sK[cur] + ((16 + l16) * 16 + sw) * 8);
        #pragma unroll
        for (int mb = 0; mb < 2; mb++) {
          s[mb][0] = __builtin_amdgcn_mfma_f32_16x16x32_bf16(qf[mb][kc], kf0, s[mb][0], 0, 0, 0);
          s[mb][1] = __builtin_amdgcn_mfma_f32_16x16x32_bf16(qf[mb][kc], kf1, s[mb][1], 0, 0, 0);
        }
      }

      if (kb + 31 > qw) {  // causal mask (wave-uniform test)
        #pragma unroll
        for (int mb = 0; mb < 2; mb++)
          #pragma unroll
          for (int cc = 0; cc < 2; cc++) {
            const int col = kb + cc * 16 + l16;
            #pragma unroll
            for (int r = 0; r < 4; r++)
              if (col > qw + mb * 16 + q4 * 4 + r) s[mb][cc][r] = -1e30f;
          }
      }

      #pragma unroll
      for (int mb = 0; mb < 2; mb++)
        #pragma unroll
        for (int cc = 0; cc < 2; cc++)
          #pragma unroll
          for (int r = 0; r < 4; r++) {
            const float p = __builtin_amdgcn_exp2f(s[mb][cc][r]);
            rs[mb][r] += p;
            sPw[(mb * 16 + q4 * 4 + r) * 32 + cc * 16 + l16] = (bf16_t)p;
          }

      bf16x8 pf[2];
      #pragma unroll
      for (int mb = 0; mb < 2; mb++)
        pf[mb] = *(const bf16x8*)(sPw + (mb * 16 + l16) * 32 + q4 * 8);
      #pragma unroll
      for (int db = 0; db < 8; db++) {
        bf16x8 vf = *(const bf16x8*)(sVT[cur] + (db * 16 + l16) * 32 + q4 * 8);
        #pragma unroll
        for (int mb = 0; mb < 2; mb++)
          o[mb][db] = __builtin_amdgcn_mfma_f32_16x16x32_bf16(pf[mb], vf, o[mb][db], 0, 0, 0);
      }
    }

    __syncthreads();
  }

  #pragma unroll
  for (int mb = 0; mb < 2; mb++)
    #pragma unroll
    for (int r = 0; r < 4; r++) {
      #pragma unroll
      for (int d = 1; d < 16; d <<= 1) rs[mb][r] += __shfl_xor(rs[mb][r], d);
      rs[mb][r] = 1.0f / rs[mb][r];
    }

  #pragma unroll
  for (int mb = 0; mb < 2; mb++)
    #pragma unroll
    for (int db = 0; db < 8; db++)
      #pragma unroll
      for (int r = 0; r < 4; r++) {
        const int qrow = qw + mb * 16 + q4 * 4 + r;
        ctx[qkbase + (size_t)qrow * DMODEL + db * 16 + l16] =
            (bf16_t)(o[mb][db][r] * rs[mb][r]);
      }
}

extern "C" void kernel_launch(void* const* d_in, const int* in_sizes, int n_in,
                              void* d_out, int out_size, void* d_ws, size_t ws_size,
                              hipStream_t stream) {
  const size_t szX = (size_t)MTOK * DMODEL;     // 16,777,216
  const size_t szW = (size_t)DMODEL * DMODEL;   // 4,194,304

  char* ws = (char*)d_ws;
  int*    flag = (int*)ws;       ws += 256;
  bf16_t* xb   = (bf16_t*)ws;    ws += szX * 2;
  bf16_t* Q    = (bf16_t*)ws;    ws += szX * 2;
  bf16_t* K_   = (bf16_t*)ws;    ws += szX * 2;
  bf16_t* VT   = (bf16_t*)ws;    ws += szX * 2;   // [feat][tok]
  bf16_t* ctx  = xb;                               // reuse after V-GEMM

  // bf16 weight parking (no extra workspace):
  bf16_t* Wq_b   = VT;              // VT dead until V-GEMM
  bf16_t* Wk_b   = VT + szW;
  bf16_t* Wv_b   = (bf16_t*)d_out;  // d_out dead until final GEMM
  bf16_t* Wout_b = K_;              // K_ free after attention
  bf16_t* bias_b = K_ + szW;

  const float kC = 0.08838834764831845f * 1.4426950408889634f;

  detect_dtype<<<1, 256, 0, stream>>>((const unsigned*)d_in[0], flag);
  convert_to_bf16<<<(int)(szX / 8 / 256), 256, 0, stream>>>(d_in[0], xb,   (int)szX, flag);
  convert_to_bf16<<<(int)(szW / 8 / 256), 256, 0, stream>>>(d_in[1], Wq_b, (int)szW, flag);
  convert_to_bf16<<<(int)(szW / 8 / 256), 256, 0, stream>>>(d_in[2], Wk_b, (int)szW, flag);
  convert_to_bf16<<<(int)(szW / 8 / 256), 256, 0, stream>>>(d_in[3], Wv_b, (int)szW, flag);

  dim3 blk(512);
  dim3 gg(DMODEL / 256, MTOK / 256);   // 8 x 32 = 256 blocks = 1/CU
  gemm256<false, false><<<gg, blk, 0, stream>>>(xb, Wq_b, nullptr, Q,  MTOK, DMODEL, DMODEL, flag, kC);
  gemm256<false, false><<<gg, blk, 0, stream>>>(xb, Wk_b, nullptr, K_, MTOK, DMODEL, DMODEL, flag, 1.0f);
  dim3 gv(MTOK / 256, DMODEL / 256);   // 32 x 8
  gemm256<false, false><<<gv, blk, 0, stream>>>(Wv_b, xb, nullptr, VT, DMODEL, MTOK, DMODEL, flag, 1.0f);

  // attn: 1D grid 1024 = 16 q-tiles x 64 (b,h); i%8 = bh%8 -> XCD-local panels
  attn_fused<<<dim3(1024), dim3(256), 0, stream>>>(Q, K_, VT, ctx);

  convert_to_bf16<<<(int)(szW / 8 / 256), 256, 0, stream>>>(d_in[4], Wout_b, (int)szW, flag);
  convert_to_bf16<<<1, 256, 0, stream>>>(d_in[5], bias_b, DMODEL, flag);
  gemm256<true, true><<<gg, blk, 0, stream>>>(ctx, Wout_b, bias_b, d_out, MTOK, DMODEL, DMODEL, flag, 1.0f);
}

// Round 5
// 567.875 us; speedup vs baseline: 1.2366x; 1.2366x over previous
//
#include <hip/hip_runtime.h>
#include <hip/hip_bf16.h>
#include <cstdint>
#include <cstddef>

typedef __bf16 bf16_t;
typedef __bf16 bf16x8 __attribute__((ext_vector_type(8)));
typedef float floatx4 __attribute__((ext_vector_type(4)));

#define BATCH 4
#define SEQ   2048
#define DMODEL 2048
#define NHEADS 16
#define HDIM  128
#define MTOK  (BATCH * SEQ)   // 8192

// async global->LDS, 16B per lane; LDS dest = wave-uniform base + lane*16
__device__ __forceinline__ void gload_lds16(const bf16_t* g, bf16_t* l) {
  __builtin_amdgcn_global_load_lds(
      (const __attribute__((address_space(1))) void*)g,
      (__attribute__((address_space(3))) void*)l, 16, 0, 0);
}

// ---------------- dtype detector ----------------
__global__ void detect_dtype(const unsigned* __restrict__ x, int* __restrict__ flag) {
  __shared__ int cnt[256];
  const int t = threadIdx.x;
  int c = 0;
  for (int i = 0; i < 8; i++) {
    unsigned w = x[t * 8 + i];
    unsigned e = (w >> 7) & 0xFFu;
    c += (e >= 100u && e <= 140u) ? 1 : 0;
  }
  cnt[t] = c;
  __syncthreads();
  for (int s = 128; s > 0; s >>= 1) {
    if (t < s) cnt[t] += cnt[t + s];
    __syncthreads();
  }
  if (t == 0) *flag = (cnt[0] > 1433) ? 1 : 0;
}

__device__ __forceinline__ bf16x8 cvt8(const float* __restrict__ p) {
  float4 a = *(const float4*)p;
  float4 b = *(const float4*)(p + 4);
  bf16x8 o;
  o[0] = (bf16_t)a.x; o[1] = (bf16_t)a.y; o[2] = (bf16_t)a.z; o[3] = (bf16_t)a.w;
  o[4] = (bf16_t)b.x; o[5] = (bf16_t)b.y; o[6] = (bf16_t)b.z; o[7] = (bf16_t)b.w;
  return o;
}

__global__ void convert_to_bf16(const void* __restrict__ src, bf16_t* __restrict__ dst,
                                int n, const int* __restrict__ flag) {
  const int i = (blockIdx.x * blockDim.x + threadIdx.x) * 8;
  if (i >= n) return;
  if (*flag) *(bf16x8*)(dst + i) = *(const bf16x8*)((const bf16_t*)src + i);
  else       *(bf16x8*)(dst + i) = cvt8((const float*)src + i);
}

// ================= 256x256 8-phase GEMM (FROZEN from r4) =================
// Three sync variants (r2/r3/r4) measured identical ~660 TF -> sync is not
// the current lever; structure frozen pending direct GEMM counters.
template<bool BIAS, bool OUT_DYN>
__global__ __launch_bounds__(512, 2)
void gemm256(const bf16_t* __restrict__ A, const bf16_t* __restrict__ B,
             const bf16_t* __restrict__ biasv, void* __restrict__ Cv,
             int M, int N, int K, const int* __restrict__ flag, float scale) {
  const bool isbf = (*flag != 0);
  __shared__ alignas(16) bf16_t sA[2][2][256 * 32];
  __shared__ alignas(16) bf16_t sB[2][2][256 * 32];
  const int tid  = threadIdx.x;
  const int lane = tid & 63;
  const int wave = tid >> 6;
  const int wm = wave >> 2, wn = wave & 3;   // 2 x 4
  const int q4 = lane >> 4, l16 = lane & 15;
  const int m0 = blockIdx.y * 256;
  const int n0 = blockIdx.x * 256;
  const int NT = K >> 6;                     // K-tiles of BK=64

  auto STG = [&](const bf16_t* __restrict__ G, int grow0, bf16_t* slot, int kt, int kh) {
    #pragma unroll
    for (int j = 0; j < 2; ++j) {
      const int c = (wave * 2 + j) * 64 + lane;   // granule 0..1023
      const int row = c >> 2, c8 = c & 3;
      gload_lds16(G + (size_t)(grow0 + row) * K + (kt * 64 + kh * 32 + c8 * 8),
                  slot + (wave * 2 + j) * 512);
    }
  };

  floatx4 acc[8][4] = {};

  const int aoff = (wm * 128 + l16) * 32 + q4 * 8;
  const int boff = (wn * 64  + l16) * 32 + q4 * 8;

  // prologue: A0(0) B0(0) A1(0) B1(0) A0(1) B0(1) -> 12 vmem ops/wave
  STG(A, m0, &sA[0][0][0], 0, 0);
  STG(B, n0, &sB[0][0][0], 0, 0);
  STG(A, m0, &sA[0][1][0], 0, 1);
  STG(B, n0, &sB[0][1][0], 0, 1);
  STG(A, m0, &sA[1][0][0], 1, 0);
  STG(B, n0, &sB[1][0][0], 1, 0);
  asm volatile("s_waitcnt vmcnt(8)");               // A0(0),B0(0) landed
  __builtin_amdgcn_s_barrier();

  #pragma unroll 2
  for (int kt = 0; kt < NT; ++kt) {
    const int buf = kt & 1;
    const bf16_t* sA0 = &sA[buf][0][0];
    const bf16_t* sA1 = &sA[buf][1][0];
    const bf16_t* sB0 = &sB[buf][0][0];
    const bf16_t* sB1 = &sB[buf][1][0];
    bf16x8 af[4], bfr[4];

    // ---- phase 0: khalf0, mhalf0 ----
    #pragma unroll
    for (int mf = 0; mf < 4; mf++) af[mf]  = *(const bf16x8*)(sA0 + aoff + mf * 512);
    #pragma unroll
    for (int nf = 0; nf < 4; nf++) bfr[nf] = *(const bf16x8*)(sB0 + boff + nf * 512);
    if (kt + 1 < NT) STG(A, m0, &sA[buf ^ 1][1][0], kt + 1, 1);
    __builtin_amdgcn_s_barrier();
    asm volatile("s_waitcnt lgkmcnt(0)");
    __builtin_amdgcn_s_setprio(1);
    #pragma unroll
    for (int mf = 0; mf < 4; mf++)
      #pragma unroll
      for (int nf = 0; nf < 4; nf++)
        acc[mf][nf] = __builtin_amdgcn_mfma_f32_16x16x32_bf16(af[mf], bfr[nf], acc[mf][nf], 0, 0, 0);
    __builtin_amdgcn_s_setprio(0);
    __builtin_amdgcn_s_barrier();

    // ---- phase 1: khalf0, mhalf1 (reuse bfr regs) ----
    #pragma unroll
    for (int mf = 0; mf < 4; mf++) af[mf] = *(const bf16x8*)(sA0 + aoff + (64 * 32) + mf * 512);
    if (kt + 1 < NT) STG(B, n0, &sB[buf ^ 1][1][0], kt + 1, 1);
    __builtin_amdgcn_s_barrier();
    asm volatile("s_waitcnt lgkmcnt(0)");
    __builtin_amdgcn_s_setprio(1);
    #pragma unroll
    for (int mf = 0; mf < 4; mf++)
      #pragma unroll
      for (int nf = 0; nf < 4; nf++)
        acc[4 + mf][nf] = __builtin_amdgcn_mfma_f32_16x16x32_bf16(af[mf], bfr[nf], acc[4 + mf][nf], 0, 0, 0);
    __builtin_amdgcn_s_setprio(0);
    if (kt < NT - 1) asm volatile("s_waitcnt vmcnt(8)");  // A1(kt),B1(kt) landed
    else             asm volatile("s_waitcnt vmcnt(0)");
    __builtin_amdgcn_s_barrier();

    // ---- phase 2: khalf1, mhalf0 ----
    #pragma unroll
    for (int mf = 0; mf < 4; mf++) af[mf]  = *(const bf16x8*)(sA1 + aoff + mf * 512);
    #pragma unroll
    for (int nf = 0; nf < 4; nf++) bfr[nf] = *(const bf16x8*)(sB1 + boff + nf * 512);
    if (kt + 2 < NT) STG(A, m0, &sA[buf][0][0], kt + 2, 0);
    __builtin_amdgcn_s_barrier();
    asm volatile("s_waitcnt lgkmcnt(0)");
    __builtin_amdgcn_s_setprio(1);
    #pragma unroll
    for (int mf = 0; mf < 4; mf++)
      #pragma unroll
      for (int nf = 0; nf < 4; nf++)
        acc[mf][nf] = __builtin_amdgcn_mfma_f32_16x16x32_bf16(af[mf], bfr[nf], acc[mf][nf], 0, 0, 0);
    __builtin_amdgcn_s_setprio(0);
    __builtin_amdgcn_s_barrier();

    // ---- phase 3: khalf1, mhalf1 (reuse bfr regs) ----
    #pragma unroll
    for (int mf = 0; mf < 4; mf++) af[mf] = *(const bf16x8*)(sA1 + aoff + (64 * 32) + mf * 512);
    if (kt + 2 < NT) STG(B, n0, &sB[buf][0][0], kt + 2, 0);
    __builtin_amdgcn_s_barrier();
    asm volatile("s_waitcnt lgkmcnt(0)");
    __builtin_amdgcn_s_setprio(1);
    #pragma unroll
    for (int mf = 0; mf < 4; mf++)
      #pragma unroll
      for (int nf = 0; nf < 4; nf++)
        acc[4 + mf][nf] = __builtin_amdgcn_mfma_f32_16x16x32_bf16(af[mf], bfr[nf], acc[4 + mf][nf], 0, 0, 0);
    __builtin_amdgcn_s_setprio(0);
    if (kt < NT - 2)       asm volatile("s_waitcnt vmcnt(8)");  // A0(kt+1),B0(kt+1)
    else if (kt == NT - 2) asm volatile("s_waitcnt vmcnt(4)");
    __builtin_amdgcn_s_barrier();
  }

  // epilogue
  #pragma unroll
  for (int mf = 0; mf < 8; mf++) {
    const int mrow = m0 + wm * 128 + mf * 16 + q4 * 4;
    #pragma unroll
    for (int nf = 0; nf < 4; nf++) {
      const int ncol = n0 + wn * 64 + nf * 16 + l16;
      float badd = 0.0f;
      if (BIAS) badd = (float)biasv[ncol];
      #pragma unroll
      for (int r = 0; r < 4; r++) {
        const size_t idx = (size_t)(mrow + r) * N + ncol;
        const float val = acc[mf][nf][r] * scale + badd;
        if (OUT_DYN && !isbf) ((float*)Cv)[idx] = val;
        else                  ((bf16_t*)Cv)[idx] = (bf16_t)val;
      }
    }
  }
}

// ---------------- Flash attention, causal, fixed-max softmax ----------------
// r5 = r1's proven structure (paired q-tiles, 68 uniform iters, sP stride 40,
// no VGPR cap -> 96 VGPRs, no spills) + r4's proven FETCH win (bh-major XCD
// mapping: bid%8 = bh%8 so all 8 pair-blocks of one (b,h) share one XCD's L2
// panel) + occupancy 2->3 blocks/CU via __launch_bounds__(256,3)
// (VGPR cap ~170 at 3 waves/SIMD, LDS 43008*3 = 126KB < 160KB).
__global__ __launch_bounds__(256, 3)
void attn_fused(const bf16_t* __restrict__ Qb, const bf16_t* __restrict__ Kb,
                const bf16_t* __restrict__ VTb, bf16_t* __restrict__ ctx) {
  __shared__ alignas(16) bf16_t sK[2][32 * 128];   // xor-swizzled 16B granules
  __shared__ alignas(16) bf16_t sVT[2][128 * 32];  // [d][t], 64B rows
  __shared__ alignas(16) bf16_t sP[4 * 32 * 40];   // per-wave [32 q][40]

  const int tid = threadIdx.x, lane = tid & 63, wave = tid >> 6;
  const int q4 = lane >> 4, l16 = lane & 15;
  const int bid = blockIdx.x;
  const int bh = bid & 63;           // bid%8 = bh%8 -> XCD-local K/V panel
  const int xp = bid >> 6;           // pair index 0..7
  const int b  = bh >> 4;
  const int h  = bh & 15;
  const size_t qkbase = (size_t)b * SEQ * DMODEL + (size_t)h * HDIM;
  const size_t vtbase = (size_t)(h * HDIM) * MTOK + (size_t)b * SEQ;
  bf16_t* sPw = sP + wave * 1280;

  auto STAGE = [&](int kt, int bs) {
    const int kb = kt * 32;
    #pragma unroll
    for (int j = 0; j < 2; ++j) {
      const int c = (wave * 2 + j) * 64 + lane;   // K: 32 rows x 16 granules
      const int row = c >> 4;
      const int gg = (c & 15) ^ (row & 15);       // xor swizzle
      gload_lds16(Kb + qkbase + (size_t)(kb + row) * DMODEL + gg * 8,
                  sK[bs] + (wave * 2 + j) * 512);
    }
    #pragma unroll
    for (int j = 0; j < 2; ++j) {
      const int c = (wave * 2 + j) * 64 + lane;   // VT: 128 rows x 4 granules
      const int row = c >> 2, g = c & 3;
      gload_lds16(VTb + vtbase + (size_t)row * MTOK + (kb + g * 8),
                  sVT[bs] + (wave * 2 + j) * 512);
    }
  };

  #pragma unroll 1
  for (int pass = 0; pass < 2; ++pass) {
    const int tile = pass ? xp : (15 - xp);   // big tile first
    const int q0 = tile * 128;
    const int qw = q0 + wave * 32;

    bf16x8 qf[2][4];
    #pragma unroll
    for (int mb = 0; mb < 2; mb++) {
      const bf16_t* qp = Qb + qkbase + (size_t)(qw + mb * 16 + l16) * DMODEL + q4 * 8;
      #pragma unroll
      for (int kc = 0; kc < 4; kc++) qf[mb][kc] = *(const bf16x8*)(qp + kc * 32);
    }

    floatx4 o[2][8] = {};
    float rs[2][4] = {};
    const int ntiles = q0 / 32 + 4;

    STAGE(0, 0);
    __syncthreads();

    for (int kt = 0; kt < ntiles; ++kt) {
      const int cur = kt & 1;
      if (kt + 1 < ntiles) STAGE(kt + 1, cur ^ 1);
      const int kb = kt * 32;

      if (kb < qw + 32) {   // skip fully-masked tiles (wave-uniform)
        floatx4 s[2][2] = {};
        #pragma unroll
        for (int kc = 0; kc < 4; kc++) {
          const int sw = (kc * 4 + q4) ^ l16;
          bf16x8 kf0 = *(const bf16x8*)(sK[cur] + ((l16)      * 16 + sw) * 8);
          bf16x8 kf1 = *(const bf16x8*)(sK[cur] + ((16 + l16) * 16 + sw) * 8);
          #pragma unroll
          for (int mb = 0; mb < 2; mb++) {
            s[mb][0] = __builtin_amdgcn_mfma_f32_16x16x32_bf16(qf[mb][kc], kf0, s[mb][0], 0, 0, 0);
            s[mb][1] = __builtin_amdgcn_mfma_f32_16x16x32_bf16(qf[mb][kc], kf1, s[mb][1], 0, 0, 0);
          }
        }

        if (kb + 31 > qw) {  // causal mask (wave-uniform test)
          #pragma unroll
          for (int mb = 0; mb < 2; mb++)
            #pragma unroll
            for (int cc = 0; cc < 2; cc++) {
              const int col = kb + cc * 16 + l16;
              #pragma unroll
              for (int r = 0; r < 4; r++)
                if (col > qw + mb * 16 + q4 * 4 + r) s[mb][cc][r] = -1e30f;
            }
        }

        #pragma unroll
        for (int mb = 0; mb < 2; mb++)
          #pragma unroll
          for (int cc = 0; cc < 2; cc++)
            #pragma unroll
            for (int r = 0; r < 4; r++) {
              const float p = __builtin_amdgcn_exp2f(s[mb][cc][r]);
              rs[mb][r] += p;
              sPw[(mb * 16 + q4 * 4 + r) * 40 + cc * 16 + l16] = (bf16_t)p;
            }

        bf16x8 pf[2];
        #pragma unroll
        for (int mb = 0; mb < 2; mb++)
          pf[mb] = *(const bf16x8*)(sPw + (mb * 16 + l16) * 40 + q4 * 8);
        #pragma unroll
        for (int db = 0; db < 8; db++) {
          bf16x8 vf = *(const bf16x8*)(sVT[cur] + (db * 16 + l16) * 32 + q4 * 8);
          #pragma unroll
          for (int mb = 0; mb < 2; mb++)
            o[mb][db] = __builtin_amdgcn_mfma_f32_16x16x32_bf16(pf[mb], vf, o[mb][db], 0, 0, 0);
        }
      }

      __syncthreads();
    }

    #pragma unroll
    for (int mb = 0; mb < 2; mb++)
      #pragma unroll
      for (int r = 0; r < 4; r++) {
        #pragma unroll
        for (int d = 1; d < 16; d <<= 1) rs[mb][r] += __shfl_xor(rs[mb][r], d);
        rs[mb][r] = 1.0f / rs[mb][r];
      }

    #pragma unroll
    for (int mb = 0; mb < 2; mb++)
      #pragma unroll
      for (int db = 0; db < 8; db++)
        #pragma unroll
        for (int r = 0; r < 4; r++) {
          const int qrow = qw + mb * 16 + q4 * 4 + r;
          ctx[qkbase + (size_t)qrow * DMODEL + db * 16 + l16] =
              (bf16_t)(o[mb][db][r] * rs[mb][r]);
        }
  }
}

extern "C" void kernel_launch(void* const* d_in, const int* in_sizes, int n_in,
                              void* d_out, int out_size, void* d_ws, size_t ws_size,
                              hipStream_t stream) {
  const size_t szX = (size_t)MTOK * DMODEL;     // 16,777,216
  const size_t szW = (size_t)DMODEL * DMODEL;   // 4,194,304

  char* ws = (char*)d_ws;
  int*    flag = (int*)ws;       ws += 256;
  bf16_t* xb   = (bf16_t*)ws;    ws += szX * 2;
  bf16_t* Q    = (bf16_t*)ws;    ws += szX * 2;
  bf16_t* K_   = (bf16_t*)ws;    ws += szX * 2;
  bf16_t* VT   = (bf16_t*)ws;    ws += szX * 2;   // [feat][tok]
  bf16_t* ctx  = xb;                               // reuse after V-GEMM

  // bf16 weight parking (no extra workspace):
  bf16_t* Wq_b   = VT;              // VT dead until V-GEMM
  bf16_t* Wk_b   = VT + szW;
  bf16_t* Wv_b   = (bf16_t*)d_out;  // d_out dead until final GEMM
  bf16_t* Wout_b = K_;              // K_ free after attention
  bf16_t* bias_b = K_ + szW;

  const float kC = 0.08838834764831845f * 1.4426950408889634f;

  detect_dtype<<<1, 256, 0, stream>>>((const unsigned*)d_in[0], flag);
  convert_to_bf16<<<(int)(szX / 8 / 256), 256, 0, stream>>>(d_in[0], xb,   (int)szX, flag);
  convert_to_bf16<<<(int)(szW / 8 / 256), 256, 0, stream>>>(d_in[1], Wq_b, (int)szW, flag);
  convert_to_bf16<<<(int)(szW / 8 / 256), 256, 0, stream>>>(d_in[2], Wk_b, (int)szW, flag);
  convert_to_bf16<<<(int)(szW / 8 / 256), 256, 0, stream>>>(d_in[3], Wv_b, (int)szW, flag);

  dim3 blk(512);
  dim3 gg(DMODEL / 256, MTOK / 256);   // 8 x 32 = 256 blocks = 1/CU
  gemm256<false, false><<<gg, blk, 0, stream>>>(xb, Wq_b, nullptr, Q,  MTOK, DMODEL, DMODEL, flag, kC);
  gemm256<false, false><<<gg, blk, 0, stream>>>(xb, Wk_b, nullptr, K_, MTOK, DMODEL, DMODEL, flag, 1.0f);
  dim3 gv(MTOK / 256, DMODEL / 256);   // 32 x 8
  gemm256<false, false><<<gv, blk, 0, stream>>>(Wv_b, xb, nullptr, VT, DMODEL, MTOK, DMODEL, flag, 1.0f);

  // attn: 512 blocks = 8 q-tile-pairs x 64 (b,h); bid%8 = bh%8 -> XCD-local
  attn_fused<<<dim3(512), dim3(256), 0, stream>>>(Q, K_, VT, ctx);

  convert_to_bf16<<<(int)(szW / 8 / 256), 256, 0, stream>>>(d_in[4], Wout_b, (int)szW, flag);
  convert_to_bf16<<<1, 256, 0, stream>>>(d_in[5], bias_b, DMODEL, flag);
  gemm256<true, true><<<gg, blk, 0, stream>>>(ctx, Wout_b, bias_b, d_out, MTOK, DMODEL, DMODEL, flag, 1.0f);
}

// Round 6
// 567.160 us; speedup vs baseline: 1.2381x; 1.0013x over previous
//
#include <hip/hip_runtime.h>
#include <hip/hip_bf16.h>
#include <cstdint>
#include <cstddef>

typedef __bf16 bf16_t;
typedef __bf16 bf16x8 __attribute__((ext_vector_type(8)));
typedef float floatx4 __attribute__((ext_vector_type(4)));

#define BATCH 4
#define SEQ   2048
#define DMODEL 2048
#define NHEADS 16
#define HDIM  128
#define MTOK  (BATCH * SEQ)   // 8192

// async global->LDS, 16B per lane; LDS dest = wave-uniform base + lane*16
__device__ __forceinline__ void gload_lds16(const bf16_t* g, bf16_t* l) {
  __builtin_amdgcn_global_load_lds(
      (const __attribute__((address_space(1))) void*)g,
      (__attribute__((address_space(3))) void*)l, 16, 0, 0);
}

// ---------------- dtype detector ----------------
__global__ void detect_dtype(const unsigned* __restrict__ x, int* __restrict__ flag) {
  __shared__ int cnt[256];
  const int t = threadIdx.x;
  int c = 0;
  for (int i = 0; i < 8; i++) {
    unsigned w = x[t * 8 + i];
    unsigned e = (w >> 7) & 0xFFu;
    c += (e >= 100u && e <= 140u) ? 1 : 0;
  }
  cnt[t] = c;
  __syncthreads();
  for (int s = 128; s > 0; s >>= 1) {
    if (t < s) cnt[t] += cnt[t + s];
    __syncthreads();
  }
  if (t == 0) *flag = (cnt[0] > 1433) ? 1 : 0;
}

__device__ __forceinline__ bf16x8 cvt8(const float* __restrict__ p) {
  float4 a = *(const float4*)p;
  float4 b = *(const float4*)(p + 4);
  bf16x8 o;
  o[0] = (bf16_t)a.x; o[1] = (bf16_t)a.y; o[2] = (bf16_t)a.z; o[3] = (bf16_t)a.w;
  o[4] = (bf16_t)b.x; o[5] = (bf16_t)b.y; o[6] = (bf16_t)b.z; o[7] = (bf16_t)b.w;
  return o;
}

__global__ void convert_to_bf16(const void* __restrict__ src, bf16_t* __restrict__ dst,
                                int n, const int* __restrict__ flag) {
  const int i = (blockIdx.x * blockDim.x + threadIdx.x) * 8;
  if (i >= n) return;
  if (*flag) *(bf16x8*)(dst + i) = *(const bf16x8*)((const bf16_t*)src + i);
  else       *(bf16x8*)(dst + i) = cvt8((const float*)src + i);
}

// ================= 256x256 8-phase GEMM =================
// Inner loop FROZEN (r2/r3/r4 sync variants identical -> not sync-bound).
// NEW (r6): XCD-aware 2D block swizzle. Default linear%8 XCD assignment put
// the same bx on every XCD -> each XCD streamed ALL of A (~33MB/XCD L2-miss
// traffic). Remap so XCD x owns a contiguous (gx/RX) x (gy/(8/RX)) region:
// per-XCD footprint = NYB A-panels + NXB B-panels (12MB for 256-blk grids),
// shared by 4-8 concurrent blocks through the 4MB L2.  Bijective for
// grids with 8 | gx*gy.
template<bool BIAS, bool OUT_DYN>
__global__ __launch_bounds__(512, 2)
void gemm256(const bf16_t* __restrict__ A, const bf16_t* __restrict__ B,
             const bf16_t* __restrict__ biasv, void* __restrict__ Cv,
             int M, int N, int K, const int* __restrict__ flag, float scale,
             int RX) {
  const bool isbf = (*flag != 0);
  __shared__ alignas(16) bf16_t sA[2][2][256 * 32];
  __shared__ alignas(16) bf16_t sB[2][2][256 * 32];
  const int tid  = threadIdx.x;
  const int lane = tid & 63;
  const int wave = tid >> 6;
  const int wm = wave >> 2, wn = wave & 3;   // 2 x 4
  const int q4 = lane >> 4, l16 = lane & 15;

  // ---- XCD-aware 2D swizzle (r6) ----
  const int lid = (int)(blockIdx.y * gridDim.x + blockIdx.x);
  const int xcd = lid & 7;
  const int j   = lid >> 3;
  const int RYr = 8 / RX;
  const int NXB = (int)gridDim.x / RX;   // blocks per region along x
  const int NYB = (int)gridDim.y / RYr;  // blocks per region along y
  const int bx  = (xcd % RX) * NXB + (j % NXB);
  const int by  = (xcd / RX) * NYB + (j / NXB);
  const int m0 = by * 256;
  const int n0 = bx * 256;
  const int NT = K >> 6;                     // K-tiles of BK=64

  auto STG = [&](const bf16_t* __restrict__ G, int grow0, bf16_t* slot, int kt, int kh) {
    #pragma unroll
    for (int jj = 0; jj < 2; ++jj) {
      const int c = (wave * 2 + jj) * 64 + lane;   // granule 0..1023
      const int row = c >> 2, c8 = c & 3;
      gload_lds16(G + (size_t)(grow0 + row) * K + (kt * 64 + kh * 32 + c8 * 8),
                  slot + (wave * 2 + jj) * 512);
    }
  };

  floatx4 acc[8][4] = {};

  const int aoff = (wm * 128 + l16) * 32 + q4 * 8;
  const int boff = (wn * 64  + l16) * 32 + q4 * 8;

  // prologue: A0(0) B0(0) A1(0) B1(0) A0(1) B0(1) -> 12 vmem ops/wave
  STG(A, m0, &sA[0][0][0], 0, 0);
  STG(B, n0, &sB[0][0][0], 0, 0);
  STG(A, m0, &sA[0][1][0], 0, 1);
  STG(B, n0, &sB[0][1][0], 0, 1);
  STG(A, m0, &sA[1][0][0], 1, 0);
  STG(B, n0, &sB[1][0][0], 1, 0);
  asm volatile("s_waitcnt vmcnt(8)");               // A0(0),B0(0) landed
  __builtin_amdgcn_s_barrier();

  #pragma unroll 2
  for (int kt = 0; kt < NT; ++kt) {
    const int buf = kt & 1;
    const bf16_t* sA0 = &sA[buf][0][0];
    const bf16_t* sA1 = &sA[buf][1][0];
    const bf16_t* sB0 = &sB[buf][0][0];
    const bf16_t* sB1 = &sB[buf][1][0];
    bf16x8 af[4], bfr[4];

    // ---- phase 0: khalf0, mhalf0 ----
    #pragma unroll
    for (int mf = 0; mf < 4; mf++) af[mf]  = *(const bf16x8*)(sA0 + aoff + mf * 512);
    #pragma unroll
    for (int nf = 0; nf < 4; nf++) bfr[nf] = *(const bf16x8*)(sB0 + boff + nf * 512);
    if (kt + 1 < NT) STG(A, m0, &sA[buf ^ 1][1][0], kt + 1, 1);
    __builtin_amdgcn_s_barrier();
    asm volatile("s_waitcnt lgkmcnt(0)");
    __builtin_amdgcn_s_setprio(1);
    #pragma unroll
    for (int mf = 0; mf < 4; mf++)
      #pragma unroll
      for (int nf = 0; nf < 4; nf++)
        acc[mf][nf] = __builtin_amdgcn_mfma_f32_16x16x32_bf16(af[mf], bfr[nf], acc[mf][nf], 0, 0, 0);
    __builtin_amdgcn_s_setprio(0);
    __builtin_amdgcn_s_barrier();

    // ---- phase 1: khalf0, mhalf1 (reuse bfr regs) ----
    #pragma unroll
    for (int mf = 0; mf < 4; mf++) af[mf] = *(const bf16x8*)(sA0 + aoff + (64 * 32) + mf * 512);
    if (kt + 1 < NT) STG(B, n0, &sB[buf ^ 1][1][0], kt + 1, 1);
    __builtin_amdgcn_s_barrier();
    asm volatile("s_waitcnt lgkmcnt(0)");
    __builtin_amdgcn_s_setprio(1);
    #pragma unroll
    for (int mf = 0; mf < 4; mf++)
      #pragma unroll
      for (int nf = 0; nf < 4; nf++)
        acc[4 + mf][nf] = __builtin_amdgcn_mfma_f32_16x16x32_bf16(af[mf], bfr[nf], acc[4 + mf][nf], 0, 0, 0);
    __builtin_amdgcn_s_setprio(0);
    if (kt < NT - 1) asm volatile("s_waitcnt vmcnt(8)");  // A1(kt),B1(kt) landed
    else             asm volatile("s_waitcnt vmcnt(0)");
    __builtin_amdgcn_s_barrier();

    // ---- phase 2: khalf1, mhalf0 ----
    #pragma unroll
    for (int mf = 0; mf < 4; mf++) af[mf]  = *(const bf16x8*)(sA1 + aoff + mf * 512);
    #pragma unroll
    for (int nf = 0; nf < 4; nf++) bfr[nf] = *(const bf16x8*)(sB1 + boff + nf * 512);
    if (kt + 2 < NT) STG(A, m0, &sA[buf][0][0], kt + 2, 0);
    __builtin_amdgcn_s_barrier();
    asm volatile("s_waitcnt lgkmcnt(0)");
    __builtin_amdgcn_s_setprio(1);
    #pragma unroll
    for (int mf = 0; mf < 4; mf++)
      #pragma unroll
      for (int nf = 0; nf < 4; nf++)
        acc[mf][nf] = __builtin_amdgcn_mfma_f32_16x16x32_bf16(af[mf], bfr[nf], acc[mf][nf], 0, 0, 0);
    __builtin_amdgcn_s_setprio(0);
    __builtin_amdgcn_s_barrier();

    // ---- phase 3: khalf1, mhalf1 (reuse bfr regs) ----
    #pragma unroll
    for (int mf = 0; mf < 4; mf++) af[mf] = *(const bf16x8*)(sA1 + aoff + (64 * 32) + mf * 512);
    if (kt + 2 < NT) STG(B, n0, &sB[buf][0][0], kt + 2, 0);
    __builtin_amdgcn_s_barrier();
    asm volatile("s_waitcnt lgkmcnt(0)");
    __builtin_amdgcn_s_setprio(1);
    #pragma unroll
    for (int mf = 0; mf < 4; mf++)
      #pragma unroll
      for (int nf = 0; nf < 4; nf++)
        acc[4 + mf][nf] = __builtin_amdgcn_mfma_f32_16x16x32_bf16(af[mf], bfr[nf], acc[4 + mf][nf], 0, 0, 0);
    __builtin_amdgcn_s_setprio(0);
    if (kt < NT - 2)       asm volatile("s_waitcnt vmcnt(8)");  // A0(kt+1),B0(kt+1)
    else if (kt == NT - 2) asm volatile("s_waitcnt vmcnt(4)");
    __builtin_amdgcn_s_barrier();
  }

  // epilogue
  #pragma unroll
  for (int mf = 0; mf < 8; mf++) {
    const int mrow = m0 + wm * 128 + mf * 16 + q4 * 4;
    #pragma unroll
    for (int nf = 0; nf < 4; nf++) {
      const int ncol = n0 + wn * 64 + nf * 16 + l16;
      float badd = 0.0f;
      if (BIAS) badd = (float)biasv[ncol];
      #pragma unroll
      for (int r = 0; r < 4; r++) {
        const size_t idx = (size_t)(mrow + r) * N + ncol;
        const float val = acc[mf][nf][r] * scale + badd;
        if (OUT_DYN && !isbf) ((float*)Cv)[idx] = val;
        else                  ((bf16_t*)Cv)[idx] = (bf16_t)val;
      }
    }
  }
}

// ---------------- Flash attention, causal, fixed-max softmax ----------------
// FROZEN from r5: paired q-tiles (68 uniform iters), sP stride 40, bh-major
// XCD mapping (FETCH 302->79MB proven), no VGPR cap (84 VGPRs, no spills).
__global__ __launch_bounds__(256, 3)
void attn_fused(const bf16_t* __restrict__ Qb, const bf16_t* __restrict__ Kb,
                const bf16_t* __restrict__ VTb, bf16_t* __restrict__ ctx) {
  __shared__ alignas(16) bf16_t sK[2][32 * 128];   // xor-swizzled 16B granules
  __shared__ alignas(16) bf16_t sVT[2][128 * 32];  // [d][t], 64B rows
  __shared__ alignas(16) bf16_t sP[4 * 32 * 40];   // per-wave [32 q][40]

  const int tid = threadIdx.x, lane = tid & 63, wave = tid >> 6;
  const int q4 = lane >> 4, l16 = lane & 15;
  const int bid = blockIdx.x;
  const int bh = bid & 63;           // bid%8 = bh%8 -> XCD-local K/V panel
  const int xp = bid >> 6;           // pair index 0..7
  const int b  = bh >> 4;
  const int h  = bh & 15;
  const size_t qkbase = (size_t)b * SEQ * DMODEL + (size_t)h * HDIM;
  const size_t vtbase = (size_t)(h * HDIM) * MTOK + (size_t)b * SEQ;
  bf16_t* sPw = sP + wave * 1280;

  auto STAGE = [&](int kt, int bs) {
    const int kb = kt * 32;
    #pragma unroll
    for (int j = 0; j < 2; ++j) {
      const int c = (wave * 2 + j) * 64 + lane;   // K: 32 rows x 16 granules
      const int row = c >> 4;
      const int gg = (c & 15) ^ (row & 15);       // xor swizzle
      gload_lds16(Kb + qkbase + (size_t)(kb + row) * DMODEL + gg * 8,
                  sK[bs] + (wave * 2 + j) * 512);
    }
    #pragma unroll
    for (int j = 0; j < 2; ++j) {
      const int c = (wave * 2 + j) * 64 + lane;   // VT: 128 rows x 4 granules
      const int row = c >> 2, g = c & 3;
      gload_lds16(VTb + vtbase + (size_t)row * MTOK + (kb + g * 8),
                  sVT[bs] + (wave * 2 + j) * 512);
    }
  };

  #pragma unroll 1
  for (int pass = 0; pass < 2; ++pass) {
    const int tile = pass ? xp : (15 - xp);   // big tile first
    const int q0 = tile * 128;
    const int qw = q0 + wave * 32;

    bf16x8 qf[2][4];
    #pragma unroll
    for (int mb = 0; mb < 2; mb++) {
      const bf16_t* qp = Qb + qkbase + (size_t)(qw + mb * 16 + l16) * DMODEL + q4 * 8;
      #pragma unroll
      for (int kc = 0; kc < 4; kc++) qf[mb][kc] = *(const bf16x8*)(qp + kc * 32);
    }

    floatx4 o[2][8] = {};
    float rs[2][4] = {};
    const int ntiles = q0 / 32 + 4;

    STAGE(0, 0);
    __syncthreads();

    for (int kt = 0; kt < ntiles; ++kt) {
      const int cur = kt & 1;
      if (kt + 1 < ntiles) STAGE(kt + 1, cur ^ 1);
      const int kb = kt * 32;

      if (kb < qw + 32) {   // skip fully-masked tiles (wave-uniform)
        floatx4 s[2][2] = {};
        #pragma unroll
        for (int kc = 0; kc < 4; kc++) {
          const int sw = (kc * 4 + q4) ^ l16;
          bf16x8 kf0 = *(const bf16x8*)(sK[cur] + ((l16)      * 16 + sw) * 8);
          bf16x8 kf1 = *(const bf16x8*)(sK[cur] + ((16 + l16) * 16 + sw) * 8);
          #pragma unroll
          for (int mb = 0; mb < 2; mb++) {
            s[mb][0] = __builtin_amdgcn_mfma_f32_16x16x32_bf16(qf[mb][kc], kf0, s[mb][0], 0, 0, 0);
            s[mb][1] = __builtin_amdgcn_mfma_f32_16x16x32_bf16(qf[mb][kc], kf1, s[mb][1], 0, 0, 0);
          }
        }

        if (kb + 31 > qw) {  // causal mask (wave-uniform test)
          #pragma unroll
          for (int mb = 0; mb < 2; mb++)
            #pragma unroll
            for (int cc = 0; cc < 2; cc++) {
              const int col = kb + cc * 16 + l16;
              #pragma unroll
              for (int r = 0; r < 4; r++)
                if (col > qw + mb * 16 + q4 * 4 + r) s[mb][cc][r] = -1e30f;
            }
        }

        #pragma unroll
        for (int mb = 0; mb < 2; mb++)
          #pragma unroll
          for (int cc = 0; cc < 2; cc++)
            #pragma unroll
            for (int r = 0; r < 4; r++) {
              const float p = __builtin_amdgcn_exp2f(s[mb][cc][r]);
              rs[mb][r] += p;
              sPw[(mb * 16 + q4 * 4 + r) * 40 + cc * 16 + l16] = (bf16_t)p;
            }

        bf16x8 pf[2];
        #pragma unroll
        for (int mb = 0; mb < 2; mb++)
          pf[mb] = *(const bf16x8*)(sPw + (mb * 16 + l16) * 40 + q4 * 8);
        #pragma unroll
        for (int db = 0; db < 8; db++) {
          bf16x8 vf = *(const bf16x8*)(sVT[cur] + (db * 16 + l16) * 32 + q4 * 8);
          #pragma unroll
          for (int mb = 0; mb < 2; mb++)
            o[mb][db] = __builtin_amdgcn_mfma_f32_16x16x32_bf16(pf[mb], vf, o[mb][db], 0, 0, 0);
        }
      }

      __syncthreads();
    }

    #pragma unroll
    for (int mb = 0; mb < 2; mb++)
      #pragma unroll
      for (int r = 0; r < 4; r++) {
        #pragma unroll
        for (int d = 1; d < 16; d <<= 1) rs[mb][r] += __shfl_xor(rs[mb][r], d);
        rs[mb][r] = 1.0f / rs[mb][r];
      }

    #pragma unroll
    for (int mb = 0; mb < 2; mb++)
      #pragma unroll
      for (int db = 0; db < 8; db++)
        #pragma unroll
        for (int r = 0; r < 4; r++) {
          const int qrow = qw + mb * 16 + q4 * 4 + r;
          ctx[qkbase + (size_t)qrow * DMODEL + db * 16 + l16] =
              (bf16_t)(o[mb][db][r] * rs[mb][r]);
        }
  }
}

extern "C" void kernel_launch(void* const* d_in, const int* in_sizes, int n_in,
                              void* d_out, int out_size, void* d_ws, size_t ws_size,
                              hipStream_t stream) {
  const size_t szX = (size_t)MTOK * DMODEL;     // 16,777,216
  const size_t szW = (size_t)DMODEL * DMODEL;   // 4,194,304

  char* ws = (char*)d_ws;
  int*    flag = (int*)ws;       ws += 256;
  bf16_t* xb   = (bf16_t*)ws;    ws += szX * 2;
  bf16_t* Q    = (bf16_t*)ws;    ws += szX * 2;
  bf16_t* K_   = (bf16_t*)ws;    ws += szX * 2;
  bf16_t* VT   = (bf16_t*)ws;    ws += szX * 2;   // [feat][tok]
  bf16_t* ctx  = xb;                               // reuse after V-GEMM

  // bf16 weight parking (no extra workspace):
  bf16_t* Wq_b   = VT;              // VT dead until V-GEMM
  bf16_t* Wk_b   = VT + szW;
  bf16_t* Wv_b   = (bf16_t*)d_out;  // d_out dead until final GEMM
  bf16_t* Wout_b = K_;              // K_ free after attention
  bf16_t* bias_b = K_ + szW;

  const float kC = 0.08838834764831845f * 1.4426950408889634f;

  detect_dtype<<<1, 256, 0, stream>>>((const unsigned*)d_in[0], flag);
  convert_to_bf16<<<(int)(szX / 8 / 256), 256, 0, stream>>>(d_in[0], xb,   (int)szX, flag);
  convert_to_bf16<<<(int)(szW / 8 / 256), 256, 0, stream>>>(d_in[1], Wq_b, (int)szW, flag);
  convert_to_bf16<<<(int)(szW / 8 / 256), 256, 0, stream>>>(d_in[2], Wk_b, (int)szW, flag);
  convert_to_bf16<<<(int)(szW / 8 / 256), 256, 0, stream>>>(d_in[3], Wv_b, (int)szW, flag);

  dim3 blk(512);
  dim3 gg(DMODEL / 256, MTOK / 256);   // 8 x 32 = 256 blocks; regions 2x4 -> RX=2
  gemm256<false, false><<<gg, blk, 0, stream>>>(xb, Wq_b, nullptr, Q,  MTOK, DMODEL, DMODEL, flag, kC, 2);
  gemm256<false, false><<<gg, blk, 0, stream>>>(xb, Wk_b, nullptr, K_, MTOK, DMODEL, DMODEL, flag, 1.0f, 2);
  dim3 gv(MTOK / 256, DMODEL / 256);   // 32 x 8 = 256 blocks; regions 4x2 -> RX=4
  gemm256<false, false><<<gv, blk, 0, stream>>>(Wv_b, xb, nullptr, VT, DMODEL, MTOK, DMODEL, flag, 1.0f, 4);

  // attn: 512 blocks = 8 q-tile-pairs x 64 (b,h); bid%8 = bh%8 -> XCD-local
  attn_fused<<<dim3(512), dim3(256), 0, stream>>>(Q, K_, VT, ctx);

  convert_to_bf16<<<(int)(szW / 8 / 256), 256, 0, stream>>>(d_in[4], Wout_b, (int)szW, flag);
  convert_to_bf16<<<1, 256, 0, stream>>>(d_in[5], bias_b, DMODEL, flag);
  gemm256<true, true><<<gg, blk, 0, stream>>>(ctx, Wout_b, bias_b, d_out, MTOK, DMODEL, DMODEL, flag, 1.0f, 2);
}